// Round 9
// baseline (287.026 us; speedup 1.0000x reference)
//
#include <hip/hip_runtime.h>

#define N_NODES 100000
#define N_EDGES 1600000
#define NUM_G   4096
#define HID     128
#define F_IN    11
#define F_PAD   16
#define F_OUT   19

#define NB      512                  // dst buckets
#define KPB     196                  // nodes per bucket: 512*196 = 100352 >= 100000
#define P01_EPB 2048                 // edges per block in P0/P1

// ---------------- helpers ----------------
__device__ inline unsigned short f32_to_bf16_rne(float x) {
    unsigned int u = __float_as_uint(x);
    u = (u + 0x7fffu + ((u >> 16) & 1u)) >> 16;
    return (unsigned short)u;
}
__device__ inline void bf16x8_to_f32(uint4 u, float f[8]) {
    f[0] = __uint_as_float(u.x << 16); f[1] = __uint_as_float(u.x & 0xffff0000u);
    f[2] = __uint_as_float(u.y << 16); f[3] = __uint_as_float(u.y & 0xffff0000u);
    f[4] = __uint_as_float(u.z << 16); f[5] = __uint_as_float(u.z & 0xffff0000u);
    f[6] = __uint_as_float(u.w << 16); f[7] = __uint_as_float(u.w & 0xffff0000u);
}

// ---------------- P0: global bucket histogram (gh pre-zeroed) ----------------
__global__ void p0_hist(const int* __restrict__ dst, int* __restrict__ gh) {
    __shared__ int h[NB];
    h[threadIdx.x] = 0; h[threadIdx.x + 256] = 0;
    __syncthreads();
    int b0 = blockIdx.x * P01_EPB;
#pragma unroll
    for (int k = 0; k < 8; ++k) {
        int e = b0 + k * 256 + threadIdx.x;
        if (e < N_EDGES) atomicAdd(&h[dst[e] / KPB], 1);
    }
    __syncthreads();
    int c = h[threadIdx.x];
    if (c) atomicAdd(&gh[threadIdx.x], c);
    c = h[threadIdx.x + 256];
    if (c) atomicAdd(&gh[threadIdx.x + 256], c);
}

// ---------------- exclusive scan of gh -> bbase, bcur ----------------
__global__ void p0_scan(const int* __restrict__ gh, int* __restrict__ bbase,
                        int* __restrict__ bcur) {
    __shared__ int tmp[NB];
    int i = threadIdx.x;
    int v = gh[i];
    tmp[i] = v;
    __syncthreads();
    for (int off = 1; off < NB; off <<= 1) {
        int t = (i >= off) ? tmp[i - off] : 0;
        __syncthreads();
        tmp[i] += t;
        __syncthreads();
    }
    bbase[i] = tmp[i] - v;
    bcur[i]  = tmp[i] - v;
    if (i == NB - 1) bbase[NB] = N_EDGES;
}

// ---------------- P1: scatter packed (src<<8 | dstLocal) into bucket regions ----------------
__global__ void p1_place(const int* __restrict__ src, const int* __restrict__ dst,
                         int* __restrict__ bcur, unsigned int* __restrict__ ebuf) {
    __shared__ int h[NB];
    __shared__ int base[NB];
    h[threadIdx.x] = 0; h[threadIdx.x + 256] = 0;
    __syncthreads();
    unsigned int pk[8]; int bn[8];
    int b0 = blockIdx.x * P01_EPB;
#pragma unroll
    for (int k = 0; k < 8; ++k) {
        int e = b0 + k * 256 + threadIdx.x;
        if (e < N_EDGES) {
            int d = dst[e];
            bn[k] = d / KPB;
            pk[k] = ((unsigned)src[e] << 8) | (unsigned)(d - bn[k] * KPB);
        } else bn[k] = -1;
    }
#pragma unroll
    for (int k = 0; k < 8; ++k)
        if (bn[k] >= 0) atomicAdd(&h[bn[k]], 1);
    __syncthreads();
    for (int j = threadIdx.x; j < NB; j += 256) {
        int c = h[j];
        base[j] = c ? atomicAdd(&bcur[j], c) : 0;
    }
    __syncthreads();
    h[threadIdx.x] = 0; h[threadIdx.x + 256] = 0;
    __syncthreads();
#pragma unroll
    for (int k = 0; k < 8; ++k) {
        if (bn[k] >= 0) {
            int r = atomicAdd(&h[bn[k]], 1);
            ebuf[base[bn[k]] + r] = pk[k];
        }
    }
}

// ---------------- P2: per-bucket CSR build + dinv + wd + xp (prep fused) ----------------
__global__ void p2_build(const unsigned int* __restrict__ ebuf, const int* __restrict__ bbase,
                         const float* __restrict__ x,
                         int* __restrict__ row_ptr, int* __restrict__ col,
                         float* __restrict__ wd, float* __restrict__ dinv,
                         float* __restrict__ xp) {
    __shared__ int hist[256];
    __shared__ int rp[256];
    __shared__ float ldinv[256];
    int b  = blockIdx.x;
    int t  = threadIdx.x;
    int dbase = b * KPB;
    int nd = N_NODES - dbase;
    if (nd > KPB) nd = KPB;
    if (nd < 0) nd = 0;
    hist[t] = 0;
    __syncthreads();
    int e0 = bbase[b], e1 = bbase[b + 1];
    for (int e = e0 + t; e < e1; e += 256)
        atomicAdd(&hist[ebuf[e] & 255u], 1);
    __syncthreads();
    int v = hist[t];
    rp[t] = v;
    __syncthreads();
    for (int off = 1; off < 256; off <<= 1) {
        int xv = (t >= off) ? rp[t - off] : 0;
        __syncthreads();
        rp[t] += xv;
        __syncthreads();
    }
    int excl = rp[t] - v;
    float di = rsqrtf(1.0f + (float)v);
    ldinv[t] = di;
    if (t < nd) {
        row_ptr[dbase + t] = e0 + excl;
        dinv[dbase + t]    = di;
    }
    if (b == NB - 1 && t == 0) row_ptr[N_NODES] = N_EDGES;
    __syncthreads();
    hist[t] = e0 + excl;           // reuse as col-position cursor
    __syncthreads();
    for (int e = e0 + t; e < e1; e += 256) {
        unsigned int w = ebuf[e];
        int dl = (int)(w & 255u);
        int pos = atomicAdd(&hist[dl], 1);
        col[pos] = (int)(w >> 8);
        wd[pos]  = ldinv[dl];      // dinv[dst] per edge, sequential
    }
    // fused prep: xp[v][0..15] = dinv[v]*x[v][f] (pad 11->16)
    for (int idx = t; idx < nd * F_PAD; idx += 256) {
        int vl = idx >> 4, f = idx & 15;
        int gv = dbase + vl;
        xp[(size_t)gv * F_PAD + f] =
            (f < F_IN) ? ldinv[vl] * x[(size_t)gv * F_IN + f] : 0.f;
    }
}

// ---------------- fused layer-1 aggregate + W1-GEMM ----------------
__global__ void agg_gemm1(const float4* __restrict__ xp4, const int* __restrict__ row_ptr,
                          const int* __restrict__ col, const float* __restrict__ dinv,
                          const float* __restrict__ W1, const float* __restrict__ b1,
                          unsigned short* __restrict__ Bh) {
    __shared__ float xs[64][F_PAD];        // 4 KB
    __shared__ float W1s[F_IN * HID];      // 5.5 KB
    __shared__ float b1s[HID];
    __shared__ float ds[64];
    int tid = threadIdx.x;
    for (int i = tid; i < F_IN * HID; i += 256) W1s[i] = W1[i];
    if (tid < HID) b1s[tid] = b1[tid];
    int v0   = blockIdx.x * 64;
    int v    = v0 + (tid >> 2);
    int lane = tid & 3;
    if (v < N_NODES) {
        if (lane == 0) ds[tid >> 2] = dinv[v];
        float4 acc = xp4[(size_t)v * 4 + lane];        // self-loop
        int j = row_ptr[v], end = row_ptr[v + 1];
        for (; j + 3 < end; j += 4) {
            int s0 = col[j], s1 = col[j + 1], s2 = col[j + 2], s3 = col[j + 3];
            float4 a0 = xp4[(size_t)s0 * 4 + lane];
            float4 a1 = xp4[(size_t)s1 * 4 + lane];
            float4 a2 = xp4[(size_t)s2 * 4 + lane];
            float4 a3 = xp4[(size_t)s3 * 4 + lane];
            acc.x += a0.x + a1.x + a2.x + a3.x;
            acc.y += a0.y + a1.y + a2.y + a3.y;
            acc.z += a0.z + a1.z + a2.z + a3.z;
            acc.w += a0.w + a1.w + a2.w + a3.w;
        }
        for (; j < end; ++j) {
            int s = col[j];
            float4 a0 = xp4[(size_t)s * 4 + lane];
            acc.x += a0.x; acc.y += a0.y; acc.z += a0.z; acc.w += a0.w;
        }
        *(float4*)&xs[tid >> 2][lane * 4] = acc;
    }
    __syncthreads();
    int jf = tid & 127;
    int n0 = tid >> 7;
    int nmax = N_NODES - v0; if (nmax > 64) nmax = 64;
#pragma unroll 4
    for (int i = 0; i < 32; ++i) {
        int n = n0 + 2 * i;
        if (n < nmax) {
            float a = 0.f;
#pragma unroll
            for (int k = 0; k < F_IN; ++k) a += xs[n][k] * W1s[k * HID + jf];
            float dv = ds[n];
            float h = fmaxf(dv * a + b1s[jf], 0.f);
            Bh[(size_t)(v0 + n) * HID + jf] = f32_to_bf16_rne(dv * h);
        }
    }
}

// ---------------- fused layer-2 aggregate + mean-pool + W2 + head ----------------
// 256 thr = 16 groups x 16 lanes; lane owns 8 feats (uint4); unroll-8 row loads.
__global__ void pool_head_fused(const unsigned short* __restrict__ Bh,
                                const float* __restrict__ dinv,
                                const int* __restrict__ row_ptr, const int* __restrict__ col,
                                const float* __restrict__ wd, const int* __restrict__ batch,
                                const float* __restrict__ W2, const float* __restrict__ b2,
                                const float* __restrict__ Wlin, const float* __restrict__ blin,
                                float* __restrict__ out) {
    __shared__ float red[16][HID + 4];
    __shared__ float r[HID];
    __shared__ float tt[HID];
    __shared__ int range[2];
    int g    = blockIdx.x;
    int tid  = threadIdx.x;
    int grp  = tid >> 4;
    int lane = tid & 15;
    if (tid < 2) {
        int tgt = g + tid;
        int lo = 0, hi = N_NODES;
        while (lo < hi) { int m = (lo + hi) >> 1; if (batch[m] < tgt) lo = m + 1; else hi = m; }
        range[tid] = lo;
    }
    __syncthreads();
    int r0 = range[0], r1 = range[1];
    const uint4* B4 = (const uint4*)Bh;
    float acc[8];
#pragma unroll
    for (int k = 0; k < 8; ++k) acc[k] = 0.f;

    // self-loop terms
    for (int v = r0 + grp; v < r1; v += 16) {
        float w = dinv[v];
        uint4 u = B4[(size_t)v * 16 + lane];
        float f8[8]; bf16x8_to_f32(u, f8);
#pragma unroll
        for (int k = 0; k < 8; ++k) acc[k] += f8[k] * w;
    }
    // edge terms: unroll-8 / 2 / 1
    int e0 = row_ptr[r0], e1 = row_ptr[r1];
    int e = e0 + grp;
    for (; e + 112 < e1; e += 128) {
        int   s[8]; float w[8]; uint4 u[8];
#pragma unroll
        for (int q = 0; q < 8; ++q) { s[q] = col[e + 16 * q]; w[q] = wd[e + 16 * q]; }
#pragma unroll
        for (int q = 0; q < 8; ++q) u[q] = B4[(size_t)s[q] * 16 + lane];
#pragma unroll
        for (int q = 0; q < 8; ++q) {
            float f8[8]; bf16x8_to_f32(u[q], f8);
#pragma unroll
            for (int k = 0; k < 8; ++k) acc[k] += f8[k] * w[q];
        }
    }
    for (; e + 16 < e1; e += 32) {
        int   s0 = col[e],  s1 = col[e + 16];
        float w0 = wd[e],   w1 = wd[e + 16];
        uint4 u0 = B4[(size_t)s0 * 16 + lane];
        uint4 u1 = B4[(size_t)s1 * 16 + lane];
        float f0[8], f1[8];
        bf16x8_to_f32(u0, f0); bf16x8_to_f32(u1, f1);
#pragma unroll
        for (int k = 0; k < 8; ++k) acc[k] += f0[k] * w0 + f1[k] * w1;
    }
    if (e < e1) {
        int   s0 = col[e];
        float w0 = wd[e];
        uint4 u0 = B4[(size_t)s0 * 16 + lane];
        float f0[8]; bf16x8_to_f32(u0, f0);
#pragma unroll
        for (int k = 0; k < 8; ++k) acc[k] += f0[k] * w0;
    }
    // cross-group reduction
#pragma unroll
    for (int k = 0; k < 8; ++k) red[grp][lane * 8 + k] = acc[k];
    __syncthreads();
    float cntv = (float)(r1 - r0);
    float inv  = (cntv > 0.f) ? 1.0f / cntv : 0.f;
    if (tid < HID) {
        float s = 0.f;
#pragma unroll
        for (int q = 0; q < 16; ++q) s += red[q][tid];
        r[tid] = s * inv;
    }
    __syncthreads();
    // W2 dot, split-k over the two half-blocks
    {
        int f = tid & 127, half = tid >> 7;
        float tj = 0.f;
        int k0 = half * 64;
#pragma unroll 8
        for (int k = k0; k < k0 + 64; ++k) tj += r[k] * W2[k * HID + f];
        red[half][f] = tj;
    }
    __syncthreads();
    if (tid < HID) {
        float bs = (cntv > 0.f) ? 1.0f : 0.f;
        tt[tid] = red[0][tid] + red[1][tid] + b2[tid] * bs;
    }
    __syncthreads();
    if (tid < F_OUT) {
        float o = blin[tid];
#pragma unroll 8
        for (int k = 0; k < HID; ++k) o += tt[k] * Wlin[k * F_OUT + tid];
        out[(size_t)g * F_OUT + tid] = o;
    }
}

extern "C" void kernel_launch(void* const* d_in, const int* in_sizes, int n_in,
                              void* d_out, int out_size, void* d_ws, size_t ws_size,
                              hipStream_t stream) {
    const float* x    = (const float*)d_in[0];
    const int*   esrc = (const int*)  d_in[1];
    const int*   edst = (const int*)  d_in[2];
    const int*   batch= (const int*)  d_in[3];
    const float* W1   = (const float*)d_in[4];
    const float* b1   = (const float*)d_in[5];
    const float* W2   = (const float*)d_in[6];
    const float* b2   = (const float*)d_in[7];
    const float* Wlin = (const float*)d_in[8];
    const float* blin = (const float*)d_in[9];
    float* out = (float*)d_out;

    // workspace layout (~53 MB), 16B-aligned segments
    char* p = (char*)d_ws;
    float*          dinv    = (float*)p;          p += sizeof(float) * N_NODES;
    float*          xp      = (float*)p;          p += sizeof(float) * (size_t)N_NODES * F_PAD;
    unsigned short* Bh      = (unsigned short*)p; p += sizeof(unsigned short) * (size_t)N_NODES * HID;
    unsigned int*   ebuf    = (unsigned int*)p;   p += sizeof(unsigned int) * (size_t)N_EDGES;
    int*            col     = (int*)p;            p += sizeof(int) * N_EDGES;
    float*          wd      = (float*)p;          p += sizeof(float) * N_EDGES;
    int*            row_ptr = (int*)p;            p += sizeof(int) * (N_NODES + 4);
    int*            gh      = (int*)p;            p += sizeof(int) * NB;
    int*            bbase   = (int*)p;            p += sizeof(int) * (NB + 4);
    int*            bcur    = (int*)p;            p += sizeof(int) * NB;

    const int nblk_e = (N_EDGES + P01_EPB - 1) / P01_EPB;   // 782

    // ---- CSR build (bucketed counting sort) + dinv + wd + xp ----
    hipMemsetAsync(gh, 0, sizeof(int) * NB, stream);
    p0_hist <<<nblk_e, 256, 0, stream>>>(edst, gh);
    p0_scan <<<1, NB, 0, stream>>>(gh, bbase, bcur);
    p1_place<<<nblk_e, 256, 0, stream>>>(esrc, edst, bcur, ebuf);
    p2_build<<<NB, 256, 0, stream>>>(ebuf, bbase, x, row_ptr, col, wd, dinv, xp);

    // ---- fused layer-1 aggregate + W1-GEMM ----
    agg_gemm1<<<(N_NODES + 63) / 64, 256, 0, stream>>>((const float4*)xp, row_ptr, col,
                                                       dinv, W1, b1, Bh);

    // ---- fused layer-2 aggregate + mean-pool + W2 + b2 + Wlin + blin ----
    pool_head_fused<<<NUM_G, 256, 0, stream>>>(Bh, dinv, row_ptr, col, wd, batch,
                                               W2, b2, Wlin, blin, out);
}

// Round 10
// 276.783 us; speedup vs baseline: 1.0370x; 1.0370x over previous
//
#include <hip/hip_runtime.h>

#define N_NODES 100000
#define N_EDGES 1600000
#define NUM_G   4096
#define HID     128
#define F_IN    11
#define F_PAD   16
#define F_OUT   19

#define NB      256                  // dst buckets (R8 config)
#define KPB     391                  // nodes per bucket: 256*391 = 100096 >= 100000
#define P01_EPB 2048                 // edges per block in P0/P1
#define NREG    8                    // src regions (XCD shards)
#define REGW    12500                // nodes per region: 8*12500 = 100000

// ---------------- helpers ----------------
__device__ inline unsigned short f32_to_bf16_rne(float x) {
    unsigned int u = __float_as_uint(x);
    u = (u + 0x7fffu + ((u >> 16) & 1u)) >> 16;
    return (unsigned short)u;
}
__device__ inline void bf16x8_to_f32(uint4 u, float f[8]) {
    f[0] = __uint_as_float(u.x << 16); f[1] = __uint_as_float(u.x & 0xffff0000u);
    f[2] = __uint_as_float(u.y << 16); f[3] = __uint_as_float(u.y & 0xffff0000u);
    f[4] = __uint_as_float(u.z << 16); f[5] = __uint_as_float(u.z & 0xffff0000u);
    f[6] = __uint_as_float(u.w << 16); f[7] = __uint_as_float(u.w & 0xffff0000u);
}

// ---------------- P0: global bucket histogram (gh pre-zeroed) ----------------
__global__ void p0_hist(const int* __restrict__ dst, int* __restrict__ gh) {
    __shared__ int h[NB];
    h[threadIdx.x] = 0;
    __syncthreads();
    int b0 = blockIdx.x * P01_EPB;
#pragma unroll
    for (int k = 0; k < 8; ++k) {
        int e = b0 + k * 256 + threadIdx.x;
        if (e < N_EDGES) atomicAdd(&h[dst[e] / KPB], 1);
    }
    __syncthreads();
    int c = h[threadIdx.x];
    if (c) atomicAdd(&gh[threadIdx.x], c);
}

// ---------------- exclusive scan of gh -> bbase, bcur ----------------
__global__ void p0_scan(const int* __restrict__ gh, int* __restrict__ bbase,
                        int* __restrict__ bcur) {
    __shared__ int tmp[NB];
    int i = threadIdx.x;
    int v = gh[i];
    tmp[i] = v;
    __syncthreads();
    for (int off = 1; off < NB; off <<= 1) {
        int t = (i >= off) ? tmp[i - off] : 0;
        __syncthreads();
        tmp[i] += t;
        __syncthreads();
    }
    bbase[i] = tmp[i] - v;
    bcur[i]  = tmp[i] - v;
    if (i == NB - 1) bbase[NB] = N_EDGES;
}

// ---------------- P1: scatter packed (src<<9 | dstLocal) into bucket regions ----------------
__global__ void p1_place(const int* __restrict__ src, const int* __restrict__ dst,
                         int* __restrict__ bcur, unsigned int* __restrict__ ebuf) {
    __shared__ int h[NB];
    __shared__ int base[NB];
    h[threadIdx.x] = 0;
    __syncthreads();
    unsigned int pk[8]; int bn[8];
    int b0 = blockIdx.x * P01_EPB;
#pragma unroll
    for (int k = 0; k < 8; ++k) {
        int e = b0 + k * 256 + threadIdx.x;
        if (e < N_EDGES) {
            int d = dst[e];
            bn[k] = d / KPB;
            pk[k] = ((unsigned)src[e] << 9) | (unsigned)(d - bn[k] * KPB);
        } else bn[k] = -1;
    }
#pragma unroll
    for (int k = 0; k < 8; ++k)
        if (bn[k] >= 0) atomicAdd(&h[bn[k]], 1);
    __syncthreads();
    {
        int c = h[threadIdx.x];
        base[threadIdx.x] = c ? atomicAdd(&bcur[threadIdx.x], c) : 0;
    }
    __syncthreads();
    h[threadIdx.x] = 0;
    __syncthreads();
#pragma unroll
    for (int k = 0; k < 8; ++k) {
        if (bn[k] >= 0) {
            int r = atomicAdd(&h[bn[k]], 1);
            ebuf[base[bn[k]] + r] = pk[k];
        }
    }
}

// ---------------- P2: per-bucket CSR build + dinv + wd + xp ----------------
__global__ void p2_build(const unsigned int* __restrict__ ebuf, const int* __restrict__ bbase,
                         const float* __restrict__ x,
                         int* __restrict__ row_ptr, int* __restrict__ col,
                         float* __restrict__ wd, float* __restrict__ dinv,
                         float* __restrict__ xp) {
    __shared__ int hist[512];
    __shared__ int rp[512];
    __shared__ float ldinv[512];
    int b  = blockIdx.x;
    int t  = threadIdx.x;
    int dbase = b * KPB;
    int nd = N_NODES - dbase; if (nd > KPB) nd = KPB;
    hist[t] = 0;
    __syncthreads();
    int e0 = bbase[b], e1 = bbase[b + 1];
    for (int e = e0 + t; e < e1; e += 512)
        atomicAdd(&hist[ebuf[e] & 511u], 1);
    __syncthreads();
    int v = hist[t];
    rp[t] = v;
    __syncthreads();
    for (int off = 1; off < 512; off <<= 1) {
        int xv = (t >= off) ? rp[t - off] : 0;
        __syncthreads();
        rp[t] += xv;
        __syncthreads();
    }
    int excl = rp[t] - v;
    float di = rsqrtf(1.0f + (float)v);
    ldinv[t] = di;
    if (t < nd) {
        row_ptr[dbase + t] = e0 + excl;
        dinv[dbase + t]    = di;
    }
    if (b == NB - 1 && t == 0) row_ptr[N_NODES] = N_EDGES;
    __syncthreads();
    hist[t] = e0 + excl;           // reuse as col-position cursor
    __syncthreads();
    for (int e = e0 + t; e < e1; e += 512) {
        unsigned int w = ebuf[e];
        int dl = (int)(w & 511u);
        int pos = atomicAdd(&hist[dl], 1);
        col[pos] = (int)(w >> 9);
        wd[pos]  = ldinv[dl];      // dinv[dst] per edge
    }
    // fused prep: xp[v][0..15] = dinv[v]*x[v][f] (pad 11->16)
    for (int idx = t; idx < nd * F_PAD; idx += 512) {
        int vl = idx >> 4, f = idx & 15;
        int gv = dbase + vl;
        xp[(size_t)gv * F_PAD + f] =
            (f < F_IN) ? ldinv[vl] * x[(size_t)gv * F_IN + f] : 0.f;
    }
}

// ---------------- graph bounds: gb[g] = lower_bound(batch, g), gb[NUM_G] = N ----------------
__global__ void graph_bounds(const int* __restrict__ batch, int* __restrict__ gb) {
    int g = blockIdx.x * blockDim.x + threadIdx.x;
    if (g > NUM_G) return;
    if (g == NUM_G) { gb[NUM_G] = N_NODES; return; }
    int lo = 0, hi = N_NODES;
    while (lo < hi) { int m = (lo + hi) >> 1; if (batch[m] < g) lo = m + 1; else hi = m; }
    gb[g] = lo;
}

// ---------------- edge_sort8: per graph, bucket edges by src region ----------------
// writes esrc2/wd2 (region-sorted within graph) and gro[g*9 + p] region offsets.
__global__ void edge_sort8(const int* __restrict__ gb, const int* __restrict__ row_ptr,
                           const int* __restrict__ col, const float* __restrict__ wd,
                           int* __restrict__ esrc2, float* __restrict__ wd2,
                           int* __restrict__ gro) {
    __shared__ int cnt[NREG];
    __shared__ int cur[NREG];
    int g = blockIdx.x;
    int t = threadIdx.x;
    if (t < NREG) cnt[t] = 0;
    __syncthreads();
    int r0 = gb[g], r1 = gb[g + 1];
    int e0 = row_ptr[r0], e1 = row_ptr[r1];
    for (int e = e0 + t; e < e1; e += 256)
        atomicAdd(&cnt[(unsigned)col[e] / REGW], 1);
    __syncthreads();
    if (t == 0) {
        int run = e0;
#pragma unroll
        for (int p = 0; p < NREG; ++p) {
            gro[g * 9 + p] = run;
            cur[p] = run;
            run += cnt[p];
        }
        gro[g * 9 + 8] = run;      // == e1
    }
    __syncthreads();
    for (int e = e0 + t; e < e1; e += 256) {
        int s = col[e];
        int p = (unsigned)s / REGW;
        int pos = atomicAdd(&cur[p], 1);
        esrc2[pos] = s;
        wd2[pos]   = wd[e];
    }
}

// ---------------- fused layer-1 aggregate + W1-GEMM ----------------
__global__ void agg_gemm1(const float4* __restrict__ xp4, const int* __restrict__ row_ptr,
                          const int* __restrict__ col, const float* __restrict__ dinv,
                          const float* __restrict__ W1, const float* __restrict__ b1,
                          unsigned short* __restrict__ Bh) {
    __shared__ float xs[64][F_PAD];        // 4 KB
    __shared__ float W1s[F_IN * HID];      // 5.5 KB
    __shared__ float b1s[HID];
    __shared__ float ds[64];
    int tid = threadIdx.x;
    for (int i = tid; i < F_IN * HID; i += 256) W1s[i] = W1[i];
    if (tid < HID) b1s[tid] = b1[tid];
    int v0   = blockIdx.x * 64;
    int v    = v0 + (tid >> 2);
    int lane = tid & 3;
    if (v < N_NODES) {
        if (lane == 0) ds[tid >> 2] = dinv[v];
        float4 acc = xp4[(size_t)v * 4 + lane];        // self-loop
        int j = row_ptr[v], end = row_ptr[v + 1];
        for (; j + 3 < end; j += 4) {
            int s0 = col[j], s1 = col[j + 1], s2 = col[j + 2], s3 = col[j + 3];
            float4 a0 = xp4[(size_t)s0 * 4 + lane];
            float4 a1 = xp4[(size_t)s1 * 4 + lane];
            float4 a2 = xp4[(size_t)s2 * 4 + lane];
            float4 a3 = xp4[(size_t)s3 * 4 + lane];
            acc.x += a0.x + a1.x + a2.x + a3.x;
            acc.y += a0.y + a1.y + a2.y + a3.y;
            acc.z += a0.z + a1.z + a2.z + a3.z;
            acc.w += a0.w + a1.w + a2.w + a3.w;
        }
        for (; j < end; ++j) {
            int s = col[j];
            float4 a0 = xp4[(size_t)s * 4 + lane];
            acc.x += a0.x; acc.y += a0.y; acc.z += a0.z; acc.w += a0.w;
        }
        *(float4*)&xs[tid >> 2][lane * 4] = acc;
    }
    __syncthreads();
    int jf = tid & 127;
    int n0 = tid >> 7;
    int nmax = N_NODES - v0; if (nmax > 64) nmax = 64;
#pragma unroll 4
    for (int i = 0; i < 32; ++i) {
        int n = n0 + 2 * i;
        if (n < nmax) {
            float a = 0.f;
#pragma unroll
            for (int k = 0; k < F_IN; ++k) a += xs[n][k] * W1s[k * HID + jf];
            float dv = ds[n];
            float h = fmaxf(dv * a + b1s[jf], 0.f);
            Bh[(size_t)(v0 + n) * HID + jf] = f32_to_bf16_rne(dv * h);
        }
    }
}

// ---------------- pool_gather: block (g,p) sums its region's contributions ----------------
// blockIdx = g*8 + p  ->  round-robin XCD mapping puts region p on XCD p.
__global__ void pool_gather(const unsigned short* __restrict__ Bh,
                            const float* __restrict__ dinv,
                            const int* __restrict__ gb, const int* __restrict__ gro,
                            const int* __restrict__ esrc2, const float* __restrict__ wd2,
                            float* __restrict__ part) {
    __shared__ float red[16][HID + 4];
    int b    = blockIdx.x;
    int g    = b >> 3;
    int p    = b & 7;
    int tid  = threadIdx.x;
    int grp  = tid >> 4;
    int lane = tid & 15;
    const uint4* B4 = (const uint4*)Bh;
    float acc[8];
#pragma unroll
    for (int k = 0; k < 8; ++k) acc[k] = 0.f;

    // self-loop terms: graph nodes intersect region p
    {
        int r0 = gb[g], r1 = gb[g + 1];
        int vlo = p * REGW, vhi = vlo + REGW;
        if (r0 > vlo) vlo = r0;
        if (r1 < vhi) vhi = r1;
        for (int v = vlo + grp; v < vhi; v += 16) {
            float w = dinv[v];
            uint4 u = B4[(size_t)v * 16 + lane];
            float f8[8]; bf16x8_to_f32(u, f8);
#pragma unroll
            for (int k = 0; k < 8; ++k) acc[k] += f8[k] * w;
        }
    }
    // edge terms for region p
    int e0 = gro[g * 9 + p], e1 = gro[g * 9 + p + 1];
    int e = e0 + grp;
    for (; e + 16 < e1; e += 32) {
        int   s0 = esrc2[e],  s1 = esrc2[e + 16];
        float w0 = wd2[e],    w1 = wd2[e + 16];
        uint4 u0 = B4[(size_t)s0 * 16 + lane];
        uint4 u1 = B4[(size_t)s1 * 16 + lane];
        float f0[8], f1[8];
        bf16x8_to_f32(u0, f0); bf16x8_to_f32(u1, f1);
#pragma unroll
        for (int k = 0; k < 8; ++k) acc[k] += f0[k] * w0 + f1[k] * w1;
    }
    if (e < e1) {
        int   s0 = esrc2[e];
        float w0 = wd2[e];
        uint4 u0 = B4[(size_t)s0 * 16 + lane];
        float f0[8]; bf16x8_to_f32(u0, f0);
#pragma unroll
        for (int k = 0; k < 8; ++k) acc[k] += f0[k] * w0;
    }
#pragma unroll
    for (int k = 0; k < 8; ++k) red[grp][lane * 8 + k] = acc[k];
    __syncthreads();
    if (tid < HID) {
        float s = 0.f;
#pragma unroll
        for (int q = 0; q < 16; ++q) s += red[q][tid];
        part[(size_t)b * HID + tid] = s;
    }
}

// ---------------- combine partials + mean + W2 + b2 + head ----------------
__global__ void combine_head(const float* __restrict__ part, const int* __restrict__ gb,
                             const float* __restrict__ W2, const float* __restrict__ b2,
                             const float* __restrict__ Wlin, const float* __restrict__ blin,
                             float* __restrict__ out) {
    __shared__ float r[HID];
    __shared__ float tt[HID];
    int g = blockIdx.x;
    int f = threadIdx.x;                 // 0..127
    float s = 0.f;
#pragma unroll
    for (int p = 0; p < NREG; ++p) s += part[(size_t)(g * 8 + p) * HID + f];
    int cnt = gb[g + 1] - gb[g];
    float inv = (cnt > 0) ? 1.0f / (float)cnt : 0.f;
    r[f] = s * inv;
    __syncthreads();
    float bs = (cnt > 0) ? 1.0f : 0.f;
    float tj = b2[f] * bs;
#pragma unroll 8
    for (int k = 0; k < HID; ++k) tj += r[k] * W2[k * HID + f];
    tt[f] = tj;
    __syncthreads();
    if (f < F_OUT) {
        float o = blin[f];
#pragma unroll 8
        for (int k = 0; k < HID; ++k) o += tt[k] * Wlin[k * F_OUT + f];
        out[(size_t)g * F_OUT + f] = o;
    }
}

extern "C" void kernel_launch(void* const* d_in, const int* in_sizes, int n_in,
                              void* d_out, int out_size, void* d_ws, size_t ws_size,
                              hipStream_t stream) {
    const float* x    = (const float*)d_in[0];
    const int*   esrc = (const int*)  d_in[1];
    const int*   edst = (const int*)  d_in[2];
    const int*   batch= (const int*)  d_in[3];
    const float* W1   = (const float*)d_in[4];
    const float* b1   = (const float*)d_in[5];
    const float* W2   = (const float*)d_in[6];
    const float* b2   = (const float*)d_in[7];
    const float* Wlin = (const float*)d_in[8];
    const float* blin = (const float*)d_in[9];
    float* out = (float*)d_out;

    // workspace layout (~83 MB), 16B-aligned segments
    char* p = (char*)d_ws;
    float*          dinv    = (float*)p;          p += sizeof(float) * N_NODES;
    float*          xp      = (float*)p;          p += sizeof(float) * (size_t)N_NODES * F_PAD;
    unsigned short* Bh      = (unsigned short*)p; p += sizeof(unsigned short) * (size_t)N_NODES * HID;
    unsigned int*   ebuf    = (unsigned int*)p;   p += sizeof(unsigned int) * (size_t)N_EDGES;
    int*            col     = (int*)p;            p += sizeof(int) * N_EDGES;
    float*          wd      = (float*)p;          p += sizeof(float) * N_EDGES;
    int*            esrc2   = (int*)p;            p += sizeof(int) * N_EDGES;
    float*          wd2     = (float*)p;          p += sizeof(float) * N_EDGES;
    float*          part    = (float*)p;          p += sizeof(float) * (size_t)NUM_G * NREG * HID;
    int*            row_ptr = (int*)p;            p += sizeof(int) * (N_NODES + 4);
    int*            gb      = (int*)p;            p += sizeof(int) * (NUM_G + 4);
    int*            gro     = (int*)p;            p += sizeof(int) * (NUM_G * 9 + 4);
    int*            gh      = (int*)p;            p += sizeof(int) * NB;
    int*            bbase   = (int*)p;            p += sizeof(int) * (NB + 4);
    int*            bcur    = (int*)p;            p += sizeof(int) * NB;

    const int nblk_e = (N_EDGES + P01_EPB - 1) / P01_EPB;   // 782

    // ---- CSR build (bucketed counting sort) + dinv + wd + xp ----
    hipMemsetAsync(gh, 0, sizeof(int) * NB, stream);
    p0_hist <<<nblk_e, 256, 0, stream>>>(edst, gh);
    p0_scan <<<1, NB, 0, stream>>>(gh, bbase, bcur);
    p1_place<<<nblk_e, 256, 0, stream>>>(esrc, edst, bcur, ebuf);
    p2_build<<<NB, 512, 0, stream>>>(ebuf, bbase, x, row_ptr, col, wd, dinv, xp);

    // ---- graph bounds + region sort of per-graph edge lists ----
    graph_bounds<<<(NUM_G + 1 + 255) / 256, 256, 0, stream>>>(batch, gb);
    edge_sort8<<<NUM_G, 256, 0, stream>>>(gb, row_ptr, col, wd, esrc2, wd2, gro);

    // ---- fused layer-1 aggregate + W1-GEMM ----
    agg_gemm1<<<(N_NODES + 63) / 64, 256, 0, stream>>>((const float4*)xp, row_ptr, col,
                                                       dinv, W1, b1, Bh);

    // ---- XCD-sharded layer-2 aggregate + pool partials ----
    pool_gather<<<NUM_G * NREG, 256, 0, stream>>>(Bh, dinv, gb, gro, esrc2, wd2, part);

    // ---- combine + mean + W2 + b2 + Wlin + blin ----
    combine_head<<<NUM_G, HID, 0, stream>>>(part, gb, W2, b2, Wlin, blin, out);
}

// Round 11
// 273.586 us; speedup vs baseline: 1.0491x; 1.0117x over previous
//
#include <hip/hip_runtime.h>
#include <hip/hip_fp16.h>

#define N_NODES 100000
#define N_EDGES 1600000
#define NUM_G   4096
#define HID     128
#define F_IN    11
#define F_PAD   16
#define F_OUT   19

#define NB      256                  // dst buckets
#define KPB     391                  // nodes per bucket: 256*391 = 100096 >= 100000
#define P01_EPB 2048                 // edges per block in P0/P1
#define NREG    8                    // src regions (XCD shards)
#define REGW    12500                // nodes per region
#define E_TOT   (N_EDGES + N_NODES)  // edges + self pseudo-edges

// ---------------- helpers ----------------
// acc[8] += f16x8 row * w ; written to pattern-match v_fma_mix_f32
__device__ inline void acc_row_f16(float acc[8], uint4 u, float w) {
    const __half2* hp = (const __half2*)&u;
#pragma unroll
    for (int i = 0; i < 4; ++i) {
        acc[2 * i]     += __half2float(__low2half(hp[i]))  * w;
        acc[2 * i + 1] += __half2float(__high2half(hp[i])) * w;
    }
}

// ---------------- P0: global bucket histogram (gh pre-zeroed) ----------------
__global__ void p0_hist(const int* __restrict__ dst, int* __restrict__ gh) {
    __shared__ int h[NB];
    h[threadIdx.x] = 0;
    __syncthreads();
    int b0 = blockIdx.x * P01_EPB;
#pragma unroll
    for (int k = 0; k < 8; ++k) {
        int e = b0 + k * 256 + threadIdx.x;
        if (e < N_EDGES) atomicAdd(&h[dst[e] / KPB], 1);
    }
    __syncthreads();
    int c = h[threadIdx.x];
    if (c) atomicAdd(&gh[threadIdx.x], c);
}

// ---------------- exclusive scan of gh -> bbase, bcur ----------------
__global__ void p0_scan(const int* __restrict__ gh, int* __restrict__ bbase,
                        int* __restrict__ bcur) {
    __shared__ int tmp[NB];
    int i = threadIdx.x;
    int v = gh[i];
    tmp[i] = v;
    __syncthreads();
    for (int off = 1; off < NB; off <<= 1) {
        int t = (i >= off) ? tmp[i - off] : 0;
        __syncthreads();
        tmp[i] += t;
        __syncthreads();
    }
    bbase[i] = tmp[i] - v;
    bcur[i]  = tmp[i] - v;
    if (i == NB - 1) bbase[NB] = N_EDGES;
}

// ---------------- P1: scatter packed (src<<9 | dstLocal) into bucket regions ----------------
__global__ void p1_place(const int* __restrict__ src, const int* __restrict__ dst,
                         int* __restrict__ bcur, unsigned int* __restrict__ ebuf) {
    __shared__ int h[NB];
    __shared__ int base[NB];
    h[threadIdx.x] = 0;
    __syncthreads();
    unsigned int pk[8]; int bn[8];
    int b0 = blockIdx.x * P01_EPB;
#pragma unroll
    for (int k = 0; k < 8; ++k) {
        int e = b0 + k * 256 + threadIdx.x;
        if (e < N_EDGES) {
            int d = dst[e];
            bn[k] = d / KPB;
            pk[k] = ((unsigned)src[e] << 9) | (unsigned)(d - bn[k] * KPB);
        } else bn[k] = -1;
    }
#pragma unroll
    for (int k = 0; k < 8; ++k)
        if (bn[k] >= 0) atomicAdd(&h[bn[k]], 1);
    __syncthreads();
    {
        int c = h[threadIdx.x];
        base[threadIdx.x] = c ? atomicAdd(&bcur[threadIdx.x], c) : 0;
    }
    __syncthreads();
    h[threadIdx.x] = 0;
    __syncthreads();
#pragma unroll
    for (int k = 0; k < 8; ++k) {
        if (bn[k] >= 0) {
            int r = atomicAdd(&h[bn[k]], 1);
            ebuf[base[bn[k]] + r] = pk[k];
        }
    }
}

// ---------------- P2: per-bucket CSR build + dinv + wd + xp(f16) ----------------
__global__ void p2_build(const unsigned int* __restrict__ ebuf, const int* __restrict__ bbase,
                         const float* __restrict__ x,
                         int* __restrict__ row_ptr, int* __restrict__ col,
                         float* __restrict__ wd, float* __restrict__ dinv,
                         __half* __restrict__ xp) {
    __shared__ int hist[512];
    __shared__ int rp[512];
    __shared__ float ldinv[512];
    int b  = blockIdx.x;
    int t  = threadIdx.x;
    int dbase = b * KPB;
    int nd = N_NODES - dbase; if (nd > KPB) nd = KPB;
    hist[t] = 0;
    __syncthreads();
    int e0 = bbase[b], e1 = bbase[b + 1];
    for (int e = e0 + t; e < e1; e += 512)
        atomicAdd(&hist[ebuf[e] & 511u], 1);
    __syncthreads();
    int v = hist[t];
    rp[t] = v;
    __syncthreads();
    for (int off = 1; off < 512; off <<= 1) {
        int xv = (t >= off) ? rp[t - off] : 0;
        __syncthreads();
        rp[t] += xv;
        __syncthreads();
    }
    int excl = rp[t] - v;
    float di = rsqrtf(1.0f + (float)v);
    ldinv[t] = di;
    if (t < nd) {
        row_ptr[dbase + t] = e0 + excl;
        dinv[dbase + t]    = di;
    }
    if (b == NB - 1 && t == 0) row_ptr[N_NODES] = N_EDGES;
    __syncthreads();
    hist[t] = e0 + excl;           // reuse as col-position cursor
    __syncthreads();
    for (int e = e0 + t; e < e1; e += 512) {
        unsigned int w = ebuf[e];
        int dl = (int)(w & 511u);
        int pos = atomicAdd(&hist[dl], 1);
        col[pos] = (int)(w >> 9);
        wd[pos]  = ldinv[dl];      // dinv[dst] per edge
    }
    // fused prep: xp[v][0..15] = f16(dinv[v]*x[v][f]) (pad 11->16)
    for (int idx = t; idx < nd * F_PAD; idx += 512) {
        int vl = idx >> 4, f = idx & 15;
        int gv = dbase + vl;
        xp[(size_t)gv * F_PAD + f] =
            __float2half_rn((f < F_IN) ? ldinv[vl] * x[(size_t)gv * F_IN + f] : 0.f);
    }
}

// ---------------- graph bounds: gb[g] = lower_bound(batch, g), gb[NUM_G] = N ----------------
__global__ void graph_bounds(const int* __restrict__ batch, int* __restrict__ gb) {
    int g = blockIdx.x * blockDim.x + threadIdx.x;
    if (g > NUM_G) return;
    if (g == NUM_G) { gb[NUM_G] = N_NODES; return; }
    int lo = 0, hi = N_NODES;
    while (lo < hi) { int m = (lo + hi) >> 1; if (batch[m] < g) lo = m + 1; else hi = m; }
    gb[g] = lo;
}

// ---------------- edge_sort8: per graph, bucket (edges + self pseudo-edges) by src region --
// entry e: src=col[e], w=wd[e]; self v: src=v, w=dinv[v].
// packed start offset for graph g = row_ptr-edges + nodes = e0 + r0.
__global__ void edge_sort8(const int* __restrict__ gb, const int* __restrict__ row_ptr,
                           const int* __restrict__ col, const float* __restrict__ wd,
                           const float* __restrict__ dinv,
                           int* __restrict__ esrc2, float* __restrict__ wd2,
                           int* __restrict__ gro) {
    __shared__ int cnt[NREG];
    __shared__ int cur[NREG];
    int g = blockIdx.x;
    int t = threadIdx.x;
    if (t < NREG) cnt[t] = 0;
    __syncthreads();
    int r0 = gb[g], r1 = gb[g + 1];
    int e0 = row_ptr[r0], e1 = row_ptr[r1];
    for (int e = e0 + t; e < e1; e += 256)
        atomicAdd(&cnt[(unsigned)col[e] / REGW], 1);
    for (int v = r0 + t; v < r1; v += 256)
        atomicAdd(&cnt[(unsigned)v / REGW], 1);
    __syncthreads();
    if (t == 0) {
        int run = e0 + r0;
#pragma unroll
        for (int p = 0; p < NREG; ++p) {
            gro[g * 9 + p] = run;
            cur[p] = run;
            run += cnt[p];
        }
        gro[g * 9 + 8] = run;      // == e1 + r1
    }
    __syncthreads();
    for (int e = e0 + t; e < e1; e += 256) {
        int s = col[e];
        int pos = atomicAdd(&cur[(unsigned)s / REGW], 1);
        esrc2[pos] = s;
        wd2[pos]   = wd[e];
    }
    for (int v = r0 + t; v < r1; v += 256) {
        int pos = atomicAdd(&cur[(unsigned)v / REGW], 1);
        esrc2[pos] = v;
        wd2[pos]   = dinv[v];
    }
}

// ---------------- fused layer-1 aggregate + W1-GEMM (xp in f16) ----------------
__global__ void agg_gemm1(const __half* __restrict__ xp, const int* __restrict__ row_ptr,
                          const int* __restrict__ col, const float* __restrict__ dinv,
                          const float* __restrict__ W1, const float* __restrict__ b1,
                          __half* __restrict__ Bh) {
    __shared__ float xs[64][F_PAD];        // 4 KB
    __shared__ float W1s[F_IN * HID];      // 5.5 KB
    __shared__ float b1s[HID];
    __shared__ float ds[64];
    int tid = threadIdx.x;
    for (int i = tid; i < F_IN * HID; i += 256) W1s[i] = W1[i];
    if (tid < HID) b1s[tid] = b1[tid];
    const uint2* xp2 = (const uint2*)xp;   // row = 4 uint2 (4 halves each)
    int v0   = blockIdx.x * 64;
    int v    = v0 + (tid >> 2);
    int lane = tid & 3;
    if (v < N_NODES) {
        if (lane == 0) ds[tid >> 2] = dinv[v];
        float a0c, a1c, a2c, a3c;
        {
            uint2 u = xp2[(size_t)v * 4 + lane];           // self-loop
            const __half2* hp = (const __half2*)&u;
            a0c = __half2float(__low2half(hp[0]));
            a1c = __half2float(__high2half(hp[0]));
            a2c = __half2float(__low2half(hp[1]));
            a3c = __half2float(__high2half(hp[1]));
        }
        int j = row_ptr[v], end = row_ptr[v + 1];
        for (; j + 3 < end; j += 4) {
            int s0 = col[j], s1 = col[j + 1], s2 = col[j + 2], s3 = col[j + 3];
            uint2 u0 = xp2[(size_t)s0 * 4 + lane];
            uint2 u1 = xp2[(size_t)s1 * 4 + lane];
            uint2 u2 = xp2[(size_t)s2 * 4 + lane];
            uint2 u3 = xp2[(size_t)s3 * 4 + lane];
            const __half2* h0 = (const __half2*)&u0;
            const __half2* h1 = (const __half2*)&u1;
            const __half2* h2 = (const __half2*)&u2;
            const __half2* h3 = (const __half2*)&u3;
            a0c += __half2float(__low2half(h0[0]))  + __half2float(__low2half(h1[0]))
                 + __half2float(__low2half(h2[0]))  + __half2float(__low2half(h3[0]));
            a1c += __half2float(__high2half(h0[0])) + __half2float(__high2half(h1[0]))
                 + __half2float(__high2half(h2[0])) + __half2float(__high2half(h3[0]));
            a2c += __half2float(__low2half(h0[1]))  + __half2float(__low2half(h1[1]))
                 + __half2float(__low2half(h2[1]))  + __half2float(__low2half(h3[1]));
            a3c += __half2float(__high2half(h0[1])) + __half2float(__high2half(h1[1]))
                 + __half2float(__high2half(h2[1])) + __half2float(__high2half(h3[1]));
        }
        for (; j < end; ++j) {
            int s = col[j];
            uint2 u = xp2[(size_t)s * 4 + lane];
            const __half2* hp = (const __half2*)&u;
            a0c += __half2float(__low2half(hp[0]));
            a1c += __half2float(__high2half(hp[0]));
            a2c += __half2float(__low2half(hp[1]));
            a3c += __half2float(__high2half(hp[1]));
        }
        xs[tid >> 2][lane * 4 + 0] = a0c;
        xs[tid >> 2][lane * 4 + 1] = a1c;
        xs[tid >> 2][lane * 4 + 2] = a2c;
        xs[tid >> 2][lane * 4 + 3] = a3c;
    }
    __syncthreads();
    int jf = tid & 127;
    int n0 = tid >> 7;
    int nmax = N_NODES - v0; if (nmax > 64) nmax = 64;
#pragma unroll 4
    for (int i = 0; i < 32; ++i) {
        int n = n0 + 2 * i;
        if (n < nmax) {
            float a = 0.f;
#pragma unroll
            for (int k = 0; k < F_IN; ++k) a += xs[n][k] * W1s[k * HID + jf];
            float dv = ds[n];
            float h = fmaxf(dv * a + b1s[jf], 0.f);
            Bh[(size_t)(v0 + n) * HID + jf] = __float2half_rn(dv * h);
        }
    }
}

// ---------------- pool_gather: block (g,p) sums its region's entries ----------------
// blockIdx = g*8 + p -> round-robin XCD mapping keeps region p on XCD p.
__global__ void pool_gather(const __half* __restrict__ Bh,
                            const int* __restrict__ gro,
                            const int* __restrict__ esrc2, const float* __restrict__ wd2,
                            float* __restrict__ part) {
    __shared__ float red[16][HID + 4];
    int b    = blockIdx.x;
    int g    = b >> 3;
    int p    = b & 7;
    int tid  = threadIdx.x;
    int grp  = tid >> 4;
    int lane = tid & 15;
    const uint4* B4 = (const uint4*)Bh;   // row = 16 uint4 (8 halves each)
    float acc[8];
#pragma unroll
    for (int k = 0; k < 8; ++k) acc[k] = 0.f;

    int e0 = gro[g * 9 + p], e1 = gro[g * 9 + p + 1];
    int e = e0 + grp;
    for (; e + 48 < e1; e += 64) {        // unroll-4
        int   s0 = esrc2[e],      s1 = esrc2[e + 16];
        int   s2 = esrc2[e + 32], s3 = esrc2[e + 48];
        float w0 = wd2[e],        w1 = wd2[e + 16];
        float w2 = wd2[e + 32],   w3 = wd2[e + 48];
        uint4 u0 = B4[(size_t)s0 * 16 + lane];
        uint4 u1 = B4[(size_t)s1 * 16 + lane];
        uint4 u2 = B4[(size_t)s2 * 16 + lane];
        uint4 u3 = B4[(size_t)s3 * 16 + lane];
        acc_row_f16(acc, u0, w0);
        acc_row_f16(acc, u1, w1);
        acc_row_f16(acc, u2, w2);
        acc_row_f16(acc, u3, w3);
    }
    for (; e < e1; e += 16) {
        int   s0 = esrc2[e];
        float w0 = wd2[e];
        uint4 u0 = B4[(size_t)s0 * 16 + lane];
        acc_row_f16(acc, u0, w0);
    }
#pragma unroll
    for (int k = 0; k < 8; ++k) red[grp][lane * 8 + k] = acc[k];
    __syncthreads();
    if (tid < HID) {
        float s = 0.f;
#pragma unroll
        for (int q = 0; q < 16; ++q) s += red[q][tid];
        part[(size_t)b * HID + tid] = s;
    }
}

// ---------------- combine partials + mean + W2 + b2 + head ----------------
__global__ void combine_head(const float* __restrict__ part, const int* __restrict__ gb,
                             const float* __restrict__ W2, const float* __restrict__ b2,
                             const float* __restrict__ Wlin, const float* __restrict__ blin,
                             float* __restrict__ out) {
    __shared__ float r[HID];
    __shared__ float tt[HID];
    int g = blockIdx.x;
    int f = threadIdx.x;                 // 0..127
    float s = 0.f;
#pragma unroll
    for (int p = 0; p < NREG; ++p) s += part[(size_t)(g * 8 + p) * HID + f];
    int cnt = gb[g + 1] - gb[g];
    float inv = (cnt > 0) ? 1.0f / (float)cnt : 0.f;
    r[f] = s * inv;
    __syncthreads();
    float bs = (cnt > 0) ? 1.0f : 0.f;
    float tj = b2[f] * bs;
#pragma unroll 8
    for (int k = 0; k < HID; ++k) tj += r[k] * W2[k * HID + f];
    tt[f] = tj;
    __syncthreads();
    if (f < F_OUT) {
        float o = blin[f];
#pragma unroll 8
        for (int k = 0; k < HID; ++k) o += tt[k] * Wlin[k * F_OUT + f];
        out[(size_t)g * F_OUT + f] = o;
    }
}

extern "C" void kernel_launch(void* const* d_in, const int* in_sizes, int n_in,
                              void* d_out, int out_size, void* d_ws, size_t ws_size,
                              hipStream_t stream) {
    const float* x    = (const float*)d_in[0];
    const int*   esrc = (const int*)  d_in[1];
    const int*   edst = (const int*)  d_in[2];
    const int*   batch= (const int*)  d_in[3];
    const float* W1   = (const float*)d_in[4];
    const float* b1   = (const float*)d_in[5];
    const float* W2   = (const float*)d_in[6];
    const float* b2   = (const float*)d_in[7];
    const float* Wlin = (const float*)d_in[8];
    const float* blin = (const float*)d_in[9];
    float* out = (float*)d_out;

    // workspace layout (~70 MB), 16B-aligned segments
    char* p = (char*)d_ws;
    float*        dinv    = (float*)p;        p += sizeof(float) * N_NODES;
    __half*       xp      = (__half*)p;       p += sizeof(__half) * (size_t)N_NODES * F_PAD;
    __half*       Bh      = (__half*)p;       p += sizeof(__half) * (size_t)N_NODES * HID;
    unsigned int* ebuf    = (unsigned int*)p; p += sizeof(unsigned int) * (size_t)N_EDGES;
    int*          col     = (int*)p;          p += sizeof(int) * N_EDGES;
    float*        wd      = (float*)p;        p += sizeof(float) * N_EDGES;
    int*          esrc2   = (int*)p;          p += sizeof(int) * E_TOT;
    float*        wd2     = (float*)p;        p += sizeof(float) * E_TOT;
    float*        part    = (float*)p;        p += sizeof(float) * (size_t)NUM_G * NREG * HID;
    int*          row_ptr = (int*)p;          p += sizeof(int) * (N_NODES + 4);
    int*          gb      = (int*)p;          p += sizeof(int) * (NUM_G + 4);
    int*          gro     = (int*)p;          p += sizeof(int) * (NUM_G * 9 + 4);
    int*          gh      = (int*)p;          p += sizeof(int) * NB;
    int*          bbase   = (int*)p;          p += sizeof(int) * (NB + 4);
    int*          bcur    = (int*)p;          p += sizeof(int) * NB;

    const int nblk_e = (N_EDGES + P01_EPB - 1) / P01_EPB;   // 782

    // ---- CSR build (bucketed counting sort) + dinv + wd + xp ----
    hipMemsetAsync(gh, 0, sizeof(int) * NB, stream);
    p0_hist <<<nblk_e, 256, 0, stream>>>(edst, gh);
    p0_scan <<<1, NB, 0, stream>>>(gh, bbase, bcur);
    p1_place<<<nblk_e, 256, 0, stream>>>(esrc, edst, bcur, ebuf);
    p2_build<<<NB, 512, 0, stream>>>(ebuf, bbase, x, row_ptr, col, wd, dinv, xp);

    // ---- graph bounds + region sort of per-graph (edges + selfs) ----
    graph_bounds<<<(NUM_G + 1 + 255) / 256, 256, 0, stream>>>(batch, gb);
    edge_sort8<<<NUM_G, 256, 0, stream>>>(gb, row_ptr, col, wd, dinv, esrc2, wd2, gro);

    // ---- fused layer-1 aggregate + W1-GEMM ----
    agg_gemm1<<<(N_NODES + 63) / 64, 256, 0, stream>>>(xp, row_ptr, col,
                                                       dinv, W1, b1, Bh);

    // ---- XCD-sharded layer-2 aggregate + pool partials ----
    pool_gather<<<NUM_G * NREG, 256, 0, stream>>>(Bh, gro, esrc2, wd2, part);

    // ---- combine + mean + W2 + b2 + Wlin + blin ----
    combine_head<<<NUM_G, HID, 0, stream>>>(part, gb, W2, b2, Wlin, blin, out);
}

// Round 12
// 268.347 us; speedup vs baseline: 1.0696x; 1.0195x over previous
//
#include <hip/hip_runtime.h>
#include <hip/hip_fp16.h>

#define N_NODES 100000
#define N_EDGES 1600000
#define NUM_G   4096
#define HID     128
#define F_IN    11
#define F_PAD   16
#define F_OUT   19

#define NB      256                  // dst buckets
#define KPB     391                  // nodes per bucket: 256*391 = 100096 >= 100000
#define P01_EPB 2048                 // edges per block in P0/P1
#define NREG    8                    // src regions (XCD shards)
#define REGW    12500                // nodes per region
#define E_TOT   (N_EDGES + N_NODES)  // edges + self pseudo-edges
#define GPB     8                    // graphs per pool_gather block

// ---------------- helpers ----------------
// acc[8] += f16x8 row * w  (pattern-matches v_fma_mix_f32)
__device__ inline void acc_row_f16(float acc[8], uint4 u, float w) {
    const __half2* hp = (const __half2*)&u;
#pragma unroll
    for (int i = 0; i < 4; ++i) {
        acc[2 * i]     += __half2float(__low2half(hp[i]))  * w;
        acc[2 * i + 1] += __half2float(__high2half(hp[i])) * w;
    }
}

// ---------------- P0: global bucket histogram (gh pre-zeroed) ----------------
__global__ void p0_hist(const int* __restrict__ dst, int* __restrict__ gh) {
    __shared__ int h[NB];
    h[threadIdx.x] = 0;
    __syncthreads();
    int b0 = blockIdx.x * P01_EPB;
#pragma unroll
    for (int k = 0; k < 8; ++k) {
        int e = b0 + k * 256 + threadIdx.x;
        if (e < N_EDGES) atomicAdd(&h[dst[e] / KPB], 1);
    }
    __syncthreads();
    int c = h[threadIdx.x];
    if (c) atomicAdd(&gh[threadIdx.x], c);
}

// ---------------- exclusive scan of gh -> bbase, bcur ----------------
__global__ void p0_scan(const int* __restrict__ gh, int* __restrict__ bbase,
                        int* __restrict__ bcur) {
    __shared__ int tmp[NB];
    int i = threadIdx.x;
    int v = gh[i];
    tmp[i] = v;
    __syncthreads();
    for (int off = 1; off < NB; off <<= 1) {
        int t = (i >= off) ? tmp[i - off] : 0;
        __syncthreads();
        tmp[i] += t;
        __syncthreads();
    }
    bbase[i] = tmp[i] - v;
    bcur[i]  = tmp[i] - v;
    if (i == NB - 1) bbase[NB] = N_EDGES;
}

// ---------------- P1: scatter packed (src<<9 | dstLocal) into bucket regions ----------------
__global__ void p1_place(const int* __restrict__ src, const int* __restrict__ dst,
                         int* __restrict__ bcur, unsigned int* __restrict__ ebuf) {
    __shared__ int h[NB];
    __shared__ int base[NB];
    h[threadIdx.x] = 0;
    __syncthreads();
    unsigned int pk[8]; int bn[8];
    int b0 = blockIdx.x * P01_EPB;
#pragma unroll
    for (int k = 0; k < 8; ++k) {
        int e = b0 + k * 256 + threadIdx.x;
        if (e < N_EDGES) {
            int d = dst[e];
            bn[k] = d / KPB;
            pk[k] = ((unsigned)src[e] << 9) | (unsigned)(d - bn[k] * KPB);
        } else bn[k] = -1;
    }
#pragma unroll
    for (int k = 0; k < 8; ++k)
        if (bn[k] >= 0) atomicAdd(&h[bn[k]], 1);
    __syncthreads();
    {
        int c = h[threadIdx.x];
        base[threadIdx.x] = c ? atomicAdd(&bcur[threadIdx.x], c) : 0;
    }
    __syncthreads();
    h[threadIdx.x] = 0;
    __syncthreads();
#pragma unroll
    for (int k = 0; k < 8; ++k) {
        if (bn[k] >= 0) {
            int r = atomicAdd(&h[bn[k]], 1);
            ebuf[base[bn[k]] + r] = pk[k];
        }
    }
}

// ---------------- P2: per-bucket CSR build + dinv + wd + xp(f16) ----------------
__global__ void p2_build(const unsigned int* __restrict__ ebuf, const int* __restrict__ bbase,
                         const float* __restrict__ x,
                         int* __restrict__ row_ptr, int* __restrict__ col,
                         float* __restrict__ wd, float* __restrict__ dinv,
                         __half* __restrict__ xp) {
    __shared__ int hist[512];
    __shared__ int rp[512];
    __shared__ float ldinv[512];
    int b  = blockIdx.x;
    int t  = threadIdx.x;
    int dbase = b * KPB;
    int nd = N_NODES - dbase; if (nd > KPB) nd = KPB;
    hist[t] = 0;
    __syncthreads();
    int e0 = bbase[b], e1 = bbase[b + 1];
    for (int e = e0 + t; e < e1; e += 512)
        atomicAdd(&hist[ebuf[e] & 511u], 1);
    __syncthreads();
    int v = hist[t];
    rp[t] = v;
    __syncthreads();
    for (int off = 1; off < 512; off <<= 1) {
        int xv = (t >= off) ? rp[t - off] : 0;
        __syncthreads();
        rp[t] += xv;
        __syncthreads();
    }
    int excl = rp[t] - v;
    float di = rsqrtf(1.0f + (float)v);
    ldinv[t] = di;
    if (t < nd) {
        row_ptr[dbase + t] = e0 + excl;
        dinv[dbase + t]    = di;
    }
    if (b == NB - 1 && t == 0) row_ptr[N_NODES] = N_EDGES;
    __syncthreads();
    hist[t] = e0 + excl;           // reuse as col-position cursor
    __syncthreads();
    for (int e = e0 + t; e < e1; e += 512) {
        unsigned int w = ebuf[e];
        int dl = (int)(w & 511u);
        int pos = atomicAdd(&hist[dl], 1);
        col[pos] = (int)(w >> 9);
        wd[pos]  = ldinv[dl];      // dinv[dst] per edge
    }
    // fused prep: xp[v][0..15] = f16(dinv[v]*x[v][f]) (pad 11->16)
    for (int idx = t; idx < nd * F_PAD; idx += 512) {
        int vl = idx >> 4, f = idx & 15;
        int gv = dbase + vl;
        xp[(size_t)gv * F_PAD + f] =
            __float2half_rn((f < F_IN) ? ldinv[vl] * x[(size_t)gv * F_IN + f] : 0.f);
    }
}

// ---------------- graph bounds: gb[g] = lower_bound(batch, g), gb[NUM_G] = N ----------------
__global__ void graph_bounds(const int* __restrict__ batch, int* __restrict__ gb) {
    int g = blockIdx.x * blockDim.x + threadIdx.x;
    if (g > NUM_G) return;
    if (g == NUM_G) { gb[NUM_G] = N_NODES; return; }
    int lo = 0, hi = N_NODES;
    while (lo < hi) { int m = (lo + hi) >> 1; if (batch[m] < g) lo = m + 1; else hi = m; }
    gb[g] = lo;
}

// ---------------- edge_sort8: per graph, bucket (edges + selfs) by src region ----------
// entry: (src, w) packed as uint2. self v: src=v, w=dinv[v].
__global__ void edge_sort8(const int* __restrict__ gb, const int* __restrict__ row_ptr,
                           const int* __restrict__ col, const float* __restrict__ wd,
                           const float* __restrict__ dinv,
                           uint2* __restrict__ ewp, int* __restrict__ gro) {
    __shared__ int cnt[NREG];
    __shared__ int cur[NREG];
    int g = blockIdx.x;
    int t = threadIdx.x;
    if (t < NREG) cnt[t] = 0;
    __syncthreads();
    int r0 = gb[g], r1 = gb[g + 1];
    int e0 = row_ptr[r0], e1 = row_ptr[r1];
    for (int e = e0 + t; e < e1; e += 256)
        atomicAdd(&cnt[(unsigned)col[e] / REGW], 1);
    for (int v = r0 + t; v < r1; v += 256)
        atomicAdd(&cnt[(unsigned)v / REGW], 1);
    __syncthreads();
    if (t == 0) {
        int run = e0 + r0;
#pragma unroll
        for (int p = 0; p < NREG; ++p) {
            gro[g * 9 + p] = run;
            cur[p] = run;
            run += cnt[p];
        }
        gro[g * 9 + 8] = run;      // == e1 + r1
    }
    __syncthreads();
    for (int e = e0 + t; e < e1; e += 256) {
        int s = col[e];
        int pos = atomicAdd(&cur[(unsigned)s / REGW], 1);
        ewp[pos] = make_uint2((unsigned)s, __float_as_uint(wd[e]));
    }
    for (int v = r0 + t; v < r1; v += 256) {
        int pos = atomicAdd(&cur[(unsigned)v / REGW], 1);
        ewp[pos] = make_uint2((unsigned)v, __float_as_uint(dinv[v]));
    }
}

// ---------------- fused layer-1 aggregate + W1-GEMM (xp in f16) ----------------
__global__ void agg_gemm1(const __half* __restrict__ xp, const int* __restrict__ row_ptr,
                          const int* __restrict__ col, const float* __restrict__ dinv,
                          const float* __restrict__ W1, const float* __restrict__ b1,
                          __half* __restrict__ Bh) {
    __shared__ float xs[64][F_PAD];        // 4 KB
    __shared__ float W1s[F_IN * HID];      // 5.5 KB
    __shared__ float b1s[HID];
    __shared__ float ds[64];
    int tid = threadIdx.x;
    for (int i = tid; i < F_IN * HID; i += 256) W1s[i] = W1[i];
    if (tid < HID) b1s[tid] = b1[tid];
    const uint2* xp2 = (const uint2*)xp;   // row = 4 uint2 (4 halves each)
    int v0   = blockIdx.x * 64;
    int v    = v0 + (tid >> 2);
    int lane = tid & 3;
    if (v < N_NODES) {
        if (lane == 0) ds[tid >> 2] = dinv[v];
        float a0c, a1c, a2c, a3c;
        {
            uint2 u = xp2[(size_t)v * 4 + lane];           // self-loop
            const __half2* hp = (const __half2*)&u;
            a0c = __half2float(__low2half(hp[0]));
            a1c = __half2float(__high2half(hp[0]));
            a2c = __half2float(__low2half(hp[1]));
            a3c = __half2float(__high2half(hp[1]));
        }
        int j = row_ptr[v], end = row_ptr[v + 1];
        for (; j + 3 < end; j += 4) {
            int s0 = col[j], s1 = col[j + 1], s2 = col[j + 2], s3 = col[j + 3];
            uint2 u0 = xp2[(size_t)s0 * 4 + lane];
            uint2 u1 = xp2[(size_t)s1 * 4 + lane];
            uint2 u2 = xp2[(size_t)s2 * 4 + lane];
            uint2 u3 = xp2[(size_t)s3 * 4 + lane];
            const __half2* h0 = (const __half2*)&u0;
            const __half2* h1 = (const __half2*)&u1;
            const __half2* h2 = (const __half2*)&u2;
            const __half2* h3 = (const __half2*)&u3;
            a0c += __half2float(__low2half(h0[0]))  + __half2float(__low2half(h1[0]))
                 + __half2float(__low2half(h2[0]))  + __half2float(__low2half(h3[0]));
            a1c += __half2float(__high2half(h0[0])) + __half2float(__high2half(h1[0]))
                 + __half2float(__high2half(h2[0])) + __half2float(__high2half(h3[0]));
            a2c += __half2float(__low2half(h0[1]))  + __half2float(__low2half(h1[1]))
                 + __half2float(__low2half(h2[1]))  + __half2float(__low2half(h3[1]));
            a3c += __half2float(__high2half(h0[1])) + __half2float(__high2half(h1[1]))
                 + __half2float(__high2half(h2[1])) + __half2float(__high2half(h3[1]));
        }
        for (; j < end; ++j) {
            int s = col[j];
            uint2 u = xp2[(size_t)s * 4 + lane];
            const __half2* hp = (const __half2*)&u;
            a0c += __half2float(__low2half(hp[0]));
            a1c += __half2float(__high2half(hp[0]));
            a2c += __half2float(__low2half(hp[1]));
            a3c += __half2float(__high2half(hp[1]));
        }
        xs[tid >> 2][lane * 4 + 0] = a0c;
        xs[tid >> 2][lane * 4 + 1] = a1c;
        xs[tid >> 2][lane * 4 + 2] = a2c;
        xs[tid >> 2][lane * 4 + 3] = a3c;
    }
    __syncthreads();
    int jf = tid & 127;
    int n0 = tid >> 7;
    int nmax = N_NODES - v0; if (nmax > 64) nmax = 64;
#pragma unroll 4
    for (int i = 0; i < 32; ++i) {
        int n = n0 + 2 * i;
        if (n < nmax) {
            float a = 0.f;
#pragma unroll
            for (int k = 0; k < F_IN; ++k) a += xs[n][k] * W1s[k * HID + jf];
            float dv = ds[n];
            float h = fmaxf(dv * a + b1s[jf], 0.f);
            Bh[(size_t)(v0 + n) * HID + jf] = __float2half_rn(dv * h);
        }
    }
}

// ---------------- pool_gather: block (gset,p) sums 8 graphs' region-p entries --------
// blockIdx = gset*8 + p -> round-robin XCD mapping keeps region p on XCD p.
// 16 groups x 16 lanes; 2 groups per graph (stride-2 interleave); lane owns 8 feats.
__global__ void pool_gather(const __half* __restrict__ Bh,
                            const int* __restrict__ gro,
                            const uint2* __restrict__ ewp,
                            float* __restrict__ part) {
    __shared__ float red[16][HID + 4];
    int b    = blockIdx.x;
    int gset = b >> 3;
    int p    = b & 7;
    int tid  = threadIdx.x;
    int grp  = tid >> 4;
    int lane = tid & 15;
    int g    = gset * GPB + (grp >> 1);
    int half = grp & 1;
    const uint4* B4 = (const uint4*)Bh;   // row = 16 uint4 (8 halves each)
    float acc[8];
#pragma unroll
    for (int k = 0; k < 8; ++k) acc[k] = 0.f;

    int e0 = gro[g * 9 + p], e1 = gro[g * 9 + p + 1];
    int e = e0 + half;
    for (; e + 6 < e1; e += 8) {          // 4 rows in flight, stride 2
        uint2 q0 = ewp[e],     q1 = ewp[e + 2];
        uint2 q2 = ewp[e + 4], q3 = ewp[e + 6];
        uint4 u0 = B4[(size_t)q0.x * 16 + lane];
        uint4 u1 = B4[(size_t)q1.x * 16 + lane];
        uint4 u2 = B4[(size_t)q2.x * 16 + lane];
        uint4 u3 = B4[(size_t)q3.x * 16 + lane];
        acc_row_f16(acc, u0, __uint_as_float(q0.y));
        acc_row_f16(acc, u1, __uint_as_float(q1.y));
        acc_row_f16(acc, u2, __uint_as_float(q2.y));
        acc_row_f16(acc, u3, __uint_as_float(q3.y));
    }
    for (; e < e1; e += 2) {
        uint2 q0 = ewp[e];
        uint4 u0 = B4[(size_t)q0.x * 16 + lane];
        acc_row_f16(acc, u0, __uint_as_float(q0.y));
    }
#pragma unroll
    for (int k = 0; k < 8; ++k) red[grp][lane * 8 + k] = acc[k];
    __syncthreads();
    // combine group pairs, write 8 part rows
    for (int i = tid; i < GPB * HID; i += 256) {
        int gg = i >> 7, f = i & 127;
        part[(size_t)((gset * GPB + gg) * NREG + p) * HID + f] =
            red[gg * 2][f] + red[gg * 2 + 1][f];
    }
}

// ---------------- combine partials + mean + W2 + b2 + head ----------------
__global__ void combine_head(const float* __restrict__ part, const int* __restrict__ gb,
                             const float* __restrict__ W2, const float* __restrict__ b2,
                             const float* __restrict__ Wlin, const float* __restrict__ blin,
                             float* __restrict__ out) {
    __shared__ float r[HID];
    __shared__ float tt[HID];
    int g = blockIdx.x;
    int f = threadIdx.x;                 // 0..127
    float s = 0.f;
#pragma unroll
    for (int p = 0; p < NREG; ++p) s += part[(size_t)(g * NREG + p) * HID + f];
    int cnt = gb[g + 1] - gb[g];
    float inv = (cnt > 0) ? 1.0f / (float)cnt : 0.f;
    r[f] = s * inv;
    __syncthreads();
    float bs = (cnt > 0) ? 1.0f : 0.f;
    float tj = b2[f] * bs;
#pragma unroll 8
    for (int k = 0; k < HID; ++k) tj += r[k] * W2[k * HID + f];
    tt[f] = tj;
    __syncthreads();
    if (f < F_OUT) {
        float o = blin[f];
#pragma unroll 8
        for (int k = 0; k < HID; ++k) o += tt[k] * Wlin[k * F_OUT + f];
        out[(size_t)g * F_OUT + f] = o;
    }
}

extern "C" void kernel_launch(void* const* d_in, const int* in_sizes, int n_in,
                              void* d_out, int out_size, void* d_ws, size_t ws_size,
                              hipStream_t stream) {
    const float* x    = (const float*)d_in[0];
    const int*   esrc = (const int*)  d_in[1];
    const int*   edst = (const int*)  d_in[2];
    const int*   batch= (const int*)  d_in[3];
    const float* W1   = (const float*)d_in[4];
    const float* b1   = (const float*)d_in[5];
    const float* W2   = (const float*)d_in[6];
    const float* b2   = (const float*)d_in[7];
    const float* Wlin = (const float*)d_in[8];
    const float* blin = (const float*)d_in[9];
    float* out = (float*)d_out;

    // workspace layout (~70 MB), 16B-aligned segments
    char* p = (char*)d_ws;
    float*        dinv    = (float*)p;        p += sizeof(float) * N_NODES;
    __half*       xp      = (__half*)p;       p += sizeof(__half) * (size_t)N_NODES * F_PAD;
    __half*       Bh      = (__half*)p;       p += sizeof(__half) * (size_t)N_NODES * HID;
    unsigned int* ebuf    = (unsigned int*)p; p += sizeof(unsigned int) * (size_t)N_EDGES;
    int*          col     = (int*)p;          p += sizeof(int) * N_EDGES;
    float*        wd      = (float*)p;        p += sizeof(float) * N_EDGES;
    uint2*        ewp     = (uint2*)p;        p += sizeof(uint2) * (size_t)E_TOT;
    float*        part    = (float*)p;        p += sizeof(float) * (size_t)NUM_G * NREG * HID;
    int*          row_ptr = (int*)p;          p += sizeof(int) * (N_NODES + 4);
    int*          gb      = (int*)p;          p += sizeof(int) * (NUM_G + 4);
    int*          gro     = (int*)p;          p += sizeof(int) * (NUM_G * 9 + 4);
    int*          gh      = (int*)p;          p += sizeof(int) * NB;
    int*          bbase   = (int*)p;          p += sizeof(int) * (NB + 4);
    int*          bcur    = (int*)p;          p += sizeof(int) * NB;

    const int nblk_e = (N_EDGES + P01_EPB - 1) / P01_EPB;   // 782

    // ---- CSR build (bucketed counting sort) + dinv + wd + xp ----
    hipMemsetAsync(gh, 0, sizeof(int) * NB, stream);
    p0_hist <<<nblk_e, 256, 0, stream>>>(edst, gh);
    p0_scan <<<1, NB, 0, stream>>>(gh, bbase, bcur);
    p1_place<<<nblk_e, 256, 0, stream>>>(esrc, edst, bcur, ebuf);
    p2_build<<<NB, 512, 0, stream>>>(ebuf, bbase, x, row_ptr, col, wd, dinv, xp);

    // ---- graph bounds + region sort of per-graph (edges + selfs) ----
    graph_bounds<<<(NUM_G + 1 + 255) / 256, 256, 0, stream>>>(batch, gb);
    edge_sort8<<<NUM_G, 256, 0, stream>>>(gb, row_ptr, col, wd, dinv, ewp, gro);

    // ---- fused layer-1 aggregate + W1-GEMM ----
    agg_gemm1<<<(N_NODES + 63) / 64, 256, 0, stream>>>(xp, row_ptr, col,
                                                       dinv, W1, b1, Bh);

    // ---- XCD-sharded layer-2 aggregate + pool partials (8 graphs/block) ----
    pool_gather<<<(NUM_G / GPB) * NREG, 256, 0, stream>>>(Bh, gro, ewp, part);

    // ---- combine + mean + W2 + b2 + Wlin + blin ----
    combine_head<<<NUM_G, HID, 0, stream>>>(part, gb, W2, b2, Wlin, blin, out);
}

// Round 13
// 257.760 us; speedup vs baseline: 1.1135x; 1.0411x over previous
//
#include <hip/hip_runtime.h>
#include <hip/hip_fp16.h>

#define N_NODES 100000
#define N_EDGES 1600000
#define NUM_G   4096
#define HID     128
#define F_IN    11
#define F_PAD   16
#define F_OUT   19

#define NB      256                  // dst buckets
#define KPB     391                  // nodes per bucket: 256*391 = 100096 >= 100000
#define P01_EPB 2048                 // edges per block in P0/P1
#define NREG    8                    // src regions (XCD shards)
#define REGW    12500                // nodes per region
#define E_TOT   (N_EDGES + N_NODES)  // edges + self pseudo-edges
#define GPB     8                    // graphs per pool_gather block

// ---------------- helpers ----------------
// acc[8] += f16x8 * w  (pattern-matches v_fma_mix_f32)
__device__ inline void acc_row_f16(float* acc, uint4 u, float w) {
    const __half2* hp = (const __half2*)&u;
#pragma unroll
    for (int i = 0; i < 4; ++i) {
        acc[2 * i]     += __half2float(__low2half(hp[i]))  * w;
        acc[2 * i + 1] += __half2float(__high2half(hp[i])) * w;
    }
}
// acc[8] += f16x8 (unweighted)
__device__ inline void add_row_f16(float* acc, uint4 u) {
    const __half2* hp = (const __half2*)&u;
#pragma unroll
    for (int i = 0; i < 4; ++i) {
        acc[2 * i]     += __half2float(__low2half(hp[i]));
        acc[2 * i + 1] += __half2float(__high2half(hp[i]));
    }
}

// ---------------- P0: global bucket histogram (gh pre-zeroed) ----------------
__global__ void p0_hist(const int* __restrict__ dst, int* __restrict__ gh) {
    __shared__ int h[NB];
    h[threadIdx.x] = 0;
    __syncthreads();
    int b0 = blockIdx.x * P01_EPB;
    int e8 = b0 + threadIdx.x * 8;
    if (e8 + 8 <= N_EDGES) {
        int4 d0 = *(const int4*)(dst + e8);
        int4 d1 = *(const int4*)(dst + e8 + 4);
        atomicAdd(&h[d0.x / KPB], 1); atomicAdd(&h[d0.y / KPB], 1);
        atomicAdd(&h[d0.z / KPB], 1); atomicAdd(&h[d0.w / KPB], 1);
        atomicAdd(&h[d1.x / KPB], 1); atomicAdd(&h[d1.y / KPB], 1);
        atomicAdd(&h[d1.z / KPB], 1); atomicAdd(&h[d1.w / KPB], 1);
    } else {
        for (int e = e8; e < N_EDGES; ++e) atomicAdd(&h[dst[e] / KPB], 1);
    }
    __syncthreads();
    int c = h[threadIdx.x];
    if (c) atomicAdd(&gh[threadIdx.x], c);
}

// ---------------- exclusive scan of gh -> bbase, bcur ----------------
__global__ void p0_scan(const int* __restrict__ gh, int* __restrict__ bbase,
                        int* __restrict__ bcur) {
    __shared__ int tmp[NB];
    int i = threadIdx.x;
    int v = gh[i];
    tmp[i] = v;
    __syncthreads();
    for (int off = 1; off < NB; off <<= 1) {
        int t = (i >= off) ? tmp[i - off] : 0;
        __syncthreads();
        tmp[i] += t;
        __syncthreads();
    }
    bbase[i] = tmp[i] - v;
    bcur[i]  = tmp[i] - v;
    if (i == NB - 1) bbase[NB] = N_EDGES;
}

// ---------------- P1: scatter packed (src<<9 | dstLocal) into bucket regions ----------------
__global__ void p1_place(const int* __restrict__ src, const int* __restrict__ dst,
                         int* __restrict__ bcur, unsigned int* __restrict__ ebuf) {
    __shared__ int h[NB];
    __shared__ int base[NB];
    h[threadIdx.x] = 0;
    __syncthreads();
    unsigned int pk[8]; int bn[8];
    int b0 = blockIdx.x * P01_EPB;
    int e8 = b0 + threadIdx.x * 8;
    if (e8 + 8 <= N_EDGES) {
        int4 s0 = *(const int4*)(src + e8);
        int4 s1 = *(const int4*)(src + e8 + 4);
        int4 d0 = *(const int4*)(dst + e8);
        int4 d1 = *(const int4*)(dst + e8 + 4);
        int ss[8] = { s0.x, s0.y, s0.z, s0.w, s1.x, s1.y, s1.z, s1.w };
        int dd[8] = { d0.x, d0.y, d0.z, d0.w, d1.x, d1.y, d1.z, d1.w };
#pragma unroll
        for (int k = 0; k < 8; ++k) {
            bn[k] = dd[k] / KPB;
            pk[k] = ((unsigned)ss[k] << 9) | (unsigned)(dd[k] - bn[k] * KPB);
        }
    } else {
#pragma unroll
        for (int k = 0; k < 8; ++k) {
            int e = e8 + k;
            if (e < N_EDGES) {
                int d = dst[e];
                bn[k] = d / KPB;
                pk[k] = ((unsigned)src[e] << 9) | (unsigned)(d - bn[k] * KPB);
            } else bn[k] = -1;
        }
    }
#pragma unroll
    for (int k = 0; k < 8; ++k)
        if (bn[k] >= 0) atomicAdd(&h[bn[k]], 1);
    __syncthreads();
    {
        int c = h[threadIdx.x];
        base[threadIdx.x] = c ? atomicAdd(&bcur[threadIdx.x], c) : 0;
    }
    __syncthreads();
    h[threadIdx.x] = 0;
    __syncthreads();
#pragma unroll
    for (int k = 0; k < 8; ++k) {
        if (bn[k] >= 0) {
            int r = atomicAdd(&h[bn[k]], 1);
            ebuf[base[bn[k]] + r] = pk[k];
        }
    }
}

// ---------------- P2: per-bucket CSR build + dinv + wd + xp(f16) ----------------
__global__ void p2_build(const unsigned int* __restrict__ ebuf, const int* __restrict__ bbase,
                         const float* __restrict__ x,
                         int* __restrict__ row_ptr, int* __restrict__ col,
                         float* __restrict__ wd, float* __restrict__ dinv,
                         __half* __restrict__ xp) {
    __shared__ int hist[512];
    __shared__ int rp[512];
    __shared__ float ldinv[512];
    int b  = blockIdx.x;
    int t  = threadIdx.x;
    int dbase = b * KPB;
    int nd = N_NODES - dbase; if (nd > KPB) nd = KPB;
    hist[t] = 0;
    __syncthreads();
    int e0 = bbase[b], e1 = bbase[b + 1];
    for (int e = e0 + t; e < e1; e += 512)
        atomicAdd(&hist[ebuf[e] & 511u], 1);
    __syncthreads();
    int v = hist[t];
    rp[t] = v;
    __syncthreads();
    for (int off = 1; off < 512; off <<= 1) {
        int xv = (t >= off) ? rp[t - off] : 0;
        __syncthreads();
        rp[t] += xv;
        __syncthreads();
    }
    int excl = rp[t] - v;
    float di = rsqrtf(1.0f + (float)v);
    ldinv[t] = di;
    if (t < nd) {
        row_ptr[dbase + t] = e0 + excl;
        dinv[dbase + t]    = di;
    }
    if (b == NB - 1 && t == 0) row_ptr[N_NODES] = N_EDGES;
    __syncthreads();
    hist[t] = e0 + excl;           // reuse as col-position cursor
    __syncthreads();
    for (int e = e0 + t; e < e1; e += 512) {
        unsigned int w = ebuf[e];
        int dl = (int)(w & 511u);
        int pos = atomicAdd(&hist[dl], 1);
        col[pos] = (int)(w >> 9);
        wd[pos]  = ldinv[dl];      // dinv[dst] per edge
    }
    // fused prep: xp[v][0..15] = f16(dinv[v]*x[v][f]) (pad 11->16)
    for (int idx = t; idx < nd * F_PAD; idx += 512) {
        int vl = idx >> 4, f = idx & 15;
        int gv = dbase + vl;
        xp[(size_t)gv * F_PAD + f] =
            __float2half_rn((f < F_IN) ? ldinv[vl] * x[(size_t)gv * F_IN + f] : 0.f);
    }
}

// ---------------- graph bounds: gb[g] = lower_bound(batch, g), gb[NUM_G] = N ----------------
__global__ void graph_bounds(const int* __restrict__ batch, int* __restrict__ gb) {
    int g = blockIdx.x * blockDim.x + threadIdx.x;
    if (g > NUM_G) return;
    if (g == NUM_G) { gb[NUM_G] = N_NODES; return; }
    int lo = 0, hi = N_NODES;
    while (lo < hi) { int m = (lo + hi) >> 1; if (batch[m] < g) lo = m + 1; else hi = m; }
    gb[g] = lo;
}

// ---------------- edge_sort8: per graph, bucket (edges + selfs) by src region ----------
__global__ void edge_sort8(const int* __restrict__ gb, const int* __restrict__ row_ptr,
                           const int* __restrict__ col, const float* __restrict__ wd,
                           const float* __restrict__ dinv,
                           uint2* __restrict__ ewp, int* __restrict__ gro) {
    __shared__ int cnt[NREG];
    __shared__ int cur[NREG];
    int g = blockIdx.x;
    int t = threadIdx.x;
    if (t < NREG) cnt[t] = 0;
    __syncthreads();
    int r0 = gb[g], r1 = gb[g + 1];
    int e0 = row_ptr[r0], e1 = row_ptr[r1];
    for (int e = e0 + t; e < e1; e += 256)
        atomicAdd(&cnt[(unsigned)col[e] / REGW], 1);
    for (int v = r0 + t; v < r1; v += 256)
        atomicAdd(&cnt[(unsigned)v / REGW], 1);
    __syncthreads();
    if (t == 0) {
        int run = e0 + r0;
#pragma unroll
        for (int p = 0; p < NREG; ++p) {
            gro[g * 9 + p] = run;
            cur[p] = run;
            run += cnt[p];
        }
        gro[g * 9 + 8] = run;      // == e1 + r1
    }
    __syncthreads();
    for (int e = e0 + t; e < e1; e += 256) {
        int s = col[e];
        int pos = atomicAdd(&cur[(unsigned)s / REGW], 1);
        ewp[pos] = make_uint2((unsigned)s, __float_as_uint(wd[e]));
    }
    for (int v = r0 + t; v < r1; v += 256) {
        int pos = atomicAdd(&cur[(unsigned)v / REGW], 1);
        ewp[pos] = make_uint2((unsigned)v, __float_as_uint(dinv[v]));
    }
}

// ---------------- fused layer-1 aggregate + W1-GEMM (xp f16, 2 lanes/row) ----------------
__global__ void agg_gemm1(const __half* __restrict__ xp, const int* __restrict__ row_ptr,
                          const int* __restrict__ col, const float* __restrict__ dinv,
                          const float* __restrict__ W1, const float* __restrict__ b1,
                          __half* __restrict__ Bh) {
    __shared__ float xs[128][F_PAD];       // 8 KB
    __shared__ float W1s[F_IN * HID];      // 5.5 KB
    __shared__ float b1s[HID];
    __shared__ float ds[128];
    int tid = threadIdx.x;
    for (int i = tid; i < F_IN * HID; i += 256) W1s[i] = W1[i];
    if (tid < HID) b1s[tid] = b1[tid];
    const uint4* xp4 = (const uint4*)xp;   // row = 2 uint4 (8 halves each)
    int v0   = blockIdx.x * 128;
    int v    = v0 + (tid >> 1);
    int lane = tid & 1;                    // lane owns 8 feats
    if (v < N_NODES) {
        if (lane == 0) ds[tid >> 1] = dinv[v];
        float a[8];
#pragma unroll
        for (int k = 0; k < 8; ++k) a[k] = 0.f;
        add_row_f16(a, xp4[(size_t)v * 2 + lane]);         // self-loop
        int j = row_ptr[v], end = row_ptr[v + 1];
        for (; j + 3 < end; j += 4) {
            int s0 = col[j], s1 = col[j + 1], s2 = col[j + 2], s3 = col[j + 3];
            uint4 u0 = xp4[(size_t)s0 * 2 + lane];
            uint4 u1 = xp4[(size_t)s1 * 2 + lane];
            uint4 u2 = xp4[(size_t)s2 * 2 + lane];
            uint4 u3 = xp4[(size_t)s3 * 2 + lane];
            add_row_f16(a, u0); add_row_f16(a, u1);
            add_row_f16(a, u2); add_row_f16(a, u3);
        }
        for (; j < end; ++j)
            add_row_f16(a, xp4[(size_t)col[j] * 2 + lane]);
#pragma unroll
        for (int k = 0; k < 8; ++k) xs[tid >> 1][lane * 8 + k] = a[k];
    }
    __syncthreads();
    int jf   = tid & 127;
    int half = tid >> 7;
    int nmax = N_NODES - v0; if (nmax > 128) nmax = 128;
    for (int n = half; n < nmax; n += 2) {
        float a = 0.f;
#pragma unroll
        for (int k = 0; k < F_IN; ++k) a += xs[n][k] * W1s[k * HID + jf];
        float dv = ds[n];
        float h = fmaxf(dv * a + b1s[jf], 0.f);
        Bh[(size_t)(v0 + n) * HID + jf] = __float2half_rn(dv * h);
    }
}

// ---------------- pool_gather: block (gset,p); 32 groups x 8 lanes; lane owns 16 feats --
// blockIdx = gset*8 + p -> round-robin XCD mapping keeps region p on XCD p.
__global__ void pool_gather(const __half* __restrict__ Bh,
                            const int* __restrict__ gro,
                            const uint2* __restrict__ ewp,
                            float* __restrict__ part) {
    __shared__ float red[32][HID + 2];    // ~16.6 KB
    int b    = blockIdx.x;
    int gset = b >> 3;
    int p    = b & 7;
    int tid  = threadIdx.x;
    int grp  = tid >> 3;                  // 0..31
    int lane = tid & 7;                   // owns feats [lane*16, lane*16+16)
    int g    = gset * GPB + (grp >> 2);
    int q    = grp & 3;                   // quarter
    const uint4* B4 = (const uint4*)Bh;   // row = 16 uint4
    float acc[16];
#pragma unroll
    for (int k = 0; k < 16; ++k) acc[k] = 0.f;

    int e0 = gro[g * 9 + p], e1 = gro[g * 9 + p + 1];
    int e = e0 + q;
    for (; e + 4 < e1; e += 8) {          // 2 entries/iter, 4 row-loads in flight
        uint2 q0 = ewp[e], q1 = ewp[e + 4];
        uint4 u00 = B4[(size_t)q0.x * 16 + lane * 2];
        uint4 u01 = B4[(size_t)q0.x * 16 + lane * 2 + 1];
        uint4 u10 = B4[(size_t)q1.x * 16 + lane * 2];
        uint4 u11 = B4[(size_t)q1.x * 16 + lane * 2 + 1];
        float w0 = __uint_as_float(q0.y), w1 = __uint_as_float(q1.y);
        acc_row_f16(acc,     u00, w0);
        acc_row_f16(acc + 8, u01, w0);
        acc_row_f16(acc,     u10, w1);
        acc_row_f16(acc + 8, u11, w1);
    }
    for (; e < e1; e += 4) {
        uint2 q0 = ewp[e];
        uint4 u00 = B4[(size_t)q0.x * 16 + lane * 2];
        uint4 u01 = B4[(size_t)q0.x * 16 + lane * 2 + 1];
        float w0 = __uint_as_float(q0.y);
        acc_row_f16(acc,     u00, w0);
        acc_row_f16(acc + 8, u01, w0);
    }
#pragma unroll
    for (int k = 0; k < 16; ++k) red[grp][lane * 16 + k] = acc[k];
    __syncthreads();
    // combine 4 quarters per graph, write 8 part rows
    for (int i = tid; i < GPB * HID; i += 256) {
        int gg = i >> 7, f = i & 127;
        int rb = gg * 4;
        part[(size_t)((gset * GPB + gg) * NREG + p) * HID + f] =
            (red[rb][f] + red[rb + 1][f]) + (red[rb + 2][f] + red[rb + 3][f]);
    }
}

// ---------------- combine partials + mean + W2 + b2 + head ----------------
__global__ void combine_head(const float* __restrict__ part, const int* __restrict__ gb,
                             const float* __restrict__ W2, const float* __restrict__ b2,
                             const float* __restrict__ Wlin, const float* __restrict__ blin,
                             float* __restrict__ out) {
    __shared__ float r[HID];
    __shared__ float tt[HID];
    int g = blockIdx.x;
    int f = threadIdx.x;                 // 0..127
    float s = 0.f;
#pragma unroll
    for (int p = 0; p < NREG; ++p) s += part[(size_t)(g * NREG + p) * HID + f];
    int cnt = gb[g + 1] - gb[g];
    float inv = (cnt > 0) ? 1.0f / (float)cnt : 0.f;
    r[f] = s * inv;
    __syncthreads();
    float bs = (cnt > 0) ? 1.0f : 0.f;
    float tj = b2[f] * bs;
#pragma unroll 8
    for (int k = 0; k < HID; ++k) tj += r[k] * W2[k * HID + f];
    tt[f] = tj;
    __syncthreads();
    if (f < F_OUT) {
        float o = blin[f];
#pragma unroll 8
        for (int k = 0; k < HID; ++k) o += tt[k] * Wlin[k * F_OUT + f];
        out[(size_t)g * F_OUT + f] = o;
    }
}

extern "C" void kernel_launch(void* const* d_in, const int* in_sizes, int n_in,
                              void* d_out, int out_size, void* d_ws, size_t ws_size,
                              hipStream_t stream) {
    const float* x    = (const float*)d_in[0];
    const int*   esrc = (const int*)  d_in[1];
    const int*   edst = (const int*)  d_in[2];
    const int*   batch= (const int*)  d_in[3];
    const float* W1   = (const float*)d_in[4];
    const float* b1   = (const float*)d_in[5];
    const float* W2   = (const float*)d_in[6];
    const float* b2   = (const float*)d_in[7];
    const float* Wlin = (const float*)d_in[8];
    const float* blin = (const float*)d_in[9];
    float* out = (float*)d_out;

    // workspace layout (~70 MB), 16B-aligned segments
    char* p = (char*)d_ws;
    float*        dinv    = (float*)p;        p += sizeof(float) * N_NODES;
    __half*       xp      = (__half*)p;       p += sizeof(__half) * (size_t)N_NODES * F_PAD;
    __half*       Bh      = (__half*)p;       p += sizeof(__half) * (size_t)N_NODES * HID;
    unsigned int* ebuf    = (unsigned int*)p; p += sizeof(unsigned int) * (size_t)N_EDGES;
    int*          col     = (int*)p;          p += sizeof(int) * N_EDGES;
    float*        wd      = (float*)p;        p += sizeof(float) * N_EDGES;
    uint2*        ewp     = (uint2*)p;        p += sizeof(uint2) * (size_t)E_TOT;
    float*        part    = (float*)p;        p += sizeof(float) * (size_t)NUM_G * NREG * HID;
    int*          row_ptr = (int*)p;          p += sizeof(int) * (N_NODES + 4);
    int*          gb      = (int*)p;          p += sizeof(int) * (NUM_G + 4);
    int*          gro     = (int*)p;          p += sizeof(int) * (NUM_G * 9 + 4);
    int*          gh      = (int*)p;          p += sizeof(int) * NB;
    int*          bbase   = (int*)p;          p += sizeof(int) * (NB + 4);
    int*          bcur    = (int*)p;          p += sizeof(int) * NB;

    const int nblk_e = (N_EDGES + P01_EPB - 1) / P01_EPB;   // 782

    // ---- CSR build (bucketed counting sort) + dinv + wd + xp ----
    hipMemsetAsync(gh, 0, sizeof(int) * NB, stream);
    p0_hist <<<nblk_e, 256, 0, stream>>>(edst, gh);
    p0_scan <<<1, NB, 0, stream>>>(gh, bbase, bcur);
    p1_place<<<nblk_e, 256, 0, stream>>>(esrc, edst, bcur, ebuf);
    p2_build<<<NB, 512, 0, stream>>>(ebuf, bbase, x, row_ptr, col, wd, dinv, xp);

    // ---- graph bounds + region sort of per-graph (edges + selfs) ----
    graph_bounds<<<(NUM_G + 1 + 255) / 256, 256, 0, stream>>>(batch, gb);
    edge_sort8<<<NUM_G, 256, 0, stream>>>(gb, row_ptr, col, wd, dinv, ewp, gro);

    // ---- fused layer-1 aggregate + W1-GEMM ----
    agg_gemm1<<<(N_NODES + 127) / 128, 256, 0, stream>>>(xp, row_ptr, col,
                                                         dinv, W1, b1, Bh);

    // ---- XCD-sharded layer-2 aggregate + pool partials (8 graphs/block) ----
    pool_gather<<<(NUM_G / GPB) * NREG, 256, 0, stream>>>(Bh, gro, ewp, part);

    // ---- combine + mean + W2 + b2 + Wlin + blin ----
    combine_head<<<NUM_G, HID, 0, stream>>>(part, gb, W2, b2, Wlin, blin, out);
}